// Round 14
// baseline (296.503 us; speedup 1.0000x reference)
//
#include <hip/hip_runtime.h>
#include <stdint.h>

#define N_CELL 8192
#define N_DRUG 4096
#define E_CELL 262144
#define E_DRUG 131072
#define DOUT   128

typedef float f32x4 __attribute__((ext_vector_type(4)));
typedef short s16x8 __attribute__((ext_vector_type(8)));

// ---------------- workspace layout (float32 element offsets) ----------------
#define OFF_DEG_C   0u
#define OFF_DEG_D   8192u
#define OFF_CNT_C   12288u
#define OFF_CNT_D   20480u
#define OFF_CUR_C   24576u
#define OFF_CUR_D   32768u
#define OFF_START_C 36864u
#define OFF_START_D 45312u
#define OFF_EW_C    49664u
#define OFF_EW_D    311808u
#define OFF_SROW_C  442880u
#define OFF_SROW_D  705024u
#define OFF_SCOEF_C 836096u
#define OFF_SCOEF_D 1098240u
#define OFF_H_C     1229312u
#define OFF_H_D     2277888u
#define OFF_END     2802176u
// byte offsets past the f32 region
#define WT_C_BYTE   (OFF_END * 4u)          // 11,208,704
#define WT_D_BYTE   (WT_C_BYTE + 128u * 8192u * 2u)
#define PART_C_BYTE 14354432u
#define PART_D_BYTE 31131648u
#define PART_END    35325952u
// bf16 copies of x (the d_in bypass). ws appears to be ~1 GiB (poison fill size).
#define XB_C_BYTE   35325952u               // 8192*8192*2 = 134,217,728
#define XB_D_BYTE   169543680u              // 4096*4096*2 =  33,554,432
#define XB_END      203098112u

__device__ __forceinline__ unsigned short f2bf(float f) {
    union { float f; uint32_t u; } v; v.f = f;
    uint32_t u = v.u + 0x7fffu + ((v.u >> 16) & 1u);   // RNE
    return (unsigned short)(u >> 16);
}

// pack 8 f32 -> 8 bf16 (round-half-up) via v_perm
__device__ __forceinline__ s16x8 pack8(float4 x, float4 y) {
    union { float4 f; uint32_t u[4]; } a, b;
    a.f = x; b.f = y;
    union { uint32_t u[4]; s16x8 v; } r;
    r.u[0] = __builtin_amdgcn_perm(a.u[1] + 0x8000u, a.u[0] + 0x8000u, 0x07060302u);
    r.u[1] = __builtin_amdgcn_perm(a.u[3] + 0x8000u, a.u[2] + 0x8000u, 0x07060302u);
    r.u[2] = __builtin_amdgcn_perm(b.u[1] + 0x8000u, b.u[0] + 0x8000u, 0x07060302u);
    r.u[3] = __builtin_amdgcn_perm(b.u[3] + 0x8000u, b.u[2] + 0x8000u, 0x07060302u);
    return r.v;
}

// ---------------- K1: prep = init counters + zero h + build WT bf16 ----------------
__global__ __launch_bounds__(256) void k_prep(const float* __restrict__ Wc, const float* __restrict__ Wd,
                                              unsigned short* __restrict__ wtc, unsigned short* __restrict__ wtd,
                                              float* __restrict__ ws) {
    int bid = blockIdx.x, t = threadIdx.x;
    if (bid < 144) {
        int i = bid * 256 + t;
        ws[i] = (i < 12288) ? 1.0f : 0.0f;
        return;
    }
    if (bid < 1680) {
        size_t i = (size_t)(bid - 144) * 256 + t;
        ((float4*)(ws + OFF_H_C))[i] = make_float4(0.f, 0.f, 0.f, 0.f);
        return;
    }
    int tile = bid - 1680;
    const float* W; unsigned short* wt; int K;
    if (tile < 1024) { W = Wc; wt = wtc; K = N_CELL; }
    else             { W = Wd; wt = wtd; K = N_DRUG; tile -= 1024; }
    int tk = tile >> 2, tc = tile & 3;
    __shared__ float tl[32][33];
    int c = t & 31, r8 = t >> 5;
#pragma unroll
    for (int p = 0; p < 4; ++p) {
        int row = r8 + p * 8;
        tl[row][c] = W[(size_t)(tk * 32 + row) * DOUT + tc * 32 + c];
    }
    __syncthreads();
#pragma unroll
    for (int p = 0; p < 4; ++p) {
        int c2 = r8 + p * 8;
        wt[(size_t)(tc * 32 + c2) * K + tk * 32 + c] = f2bf(tl[c][c2]);
    }
}

// ---------------- K1b: pure-streaming cast x f32 -> bf16 into ws (d_in bypass) ------
// Grid-stride, 32B read / 16B write per thread-iter, perfectly coalesced, no LDS/barrier.
// This is ALSO the d_in-bandwidth probe: duration tells us the d_in read ceiling.
__global__ __launch_bounds__(256) void k_cast(const float* __restrict__ xc, const float* __restrict__ xd,
                                              unsigned short* __restrict__ xbC,
                                              unsigned short* __restrict__ xbD) {
    const size_t nC = (size_t)N_CELL * N_CELL / 8;   // 8,388,608 chunks
    const size_t nD = (size_t)N_DRUG * N_DRUG / 8;   // 2,097,152 chunks
    size_t stride = (size_t)gridDim.x * 256;
    for (size_t i = (size_t)blockIdx.x * 256 + threadIdx.x; i < nC + nD; i += stride) {
        const float4* src; unsigned short* dst; size_t j;
        if (i < nC) { src = (const float4*)xc; dst = xbC; j = i; }
        else        { src = (const float4*)xd; dst = xbD; j = i - nC; }
        float4 a = src[2 * j], b = src[2 * j + 1];
        *(s16x8*)(dst + j * 8) = pack8(a, b);
    }
}

// ---------------- K2: ew gather + deg atomic + incoming-edge count ----------------
__global__ __launch_bounds__(256) void k_edge(const float* __restrict__ xc, const int* __restrict__ ec,
                                              const float* __restrict__ xd, const int* __restrict__ ed,
                                              float* __restrict__ ws) {
    int i = blockIdx.x * 256 + threadIdx.x;
    const float* x; const int* edges; float* ew; float* deg; int* cnt; int N, E, idx;
    if (i < E_CELL) {
        idx = i; x = xc; edges = ec; N = N_CELL; E = E_CELL;
        ew = ws + OFF_EW_C; deg = ws + OFF_DEG_C; cnt = (int*)(ws + OFF_CNT_C);
    } else {
        idx = i - E_CELL; if (idx >= E_DRUG) return;
        x = xd; edges = ed; N = N_DRUG; E = E_DRUG;
        ew = ws + OFF_EW_D; deg = ws + OFF_DEG_D; cnt = (int*)(ws + OFF_CNT_D);
    }
    int r = edges[idx], c = edges[E + idx];
    float w = x[(size_t)r * N + c];
    ew[idx] = w;
    unsafeAtomicAdd(&deg[c], w);
    atomicAdd(&cnt[c], 1);
}

// ---------------- K3: dinv (blocks 0..47) + exclusive scan (blocks 48,49) ----------------
__global__ __launch_bounds__(256) void k_scan2(float* ws) {
    int bid = blockIdx.x, t = threadIdx.x;
    if (bid < 48) {
        int i = bid * 256 + t;
        float d = ws[i];
        ws[i] = d > 0.f ? rsqrtf(fmaxf(d, 1e-30f)) : 0.f;
        return;
    }
    const int* cnt; int* start; int N, chunk;
    if (bid == 48) { cnt = (const int*)(ws + OFF_CNT_C); start = (int*)(ws + OFF_START_C); N = N_CELL; chunk = 32; }
    else           { cnt = (const int*)(ws + OFF_CNT_D); start = (int*)(ws + OFF_START_D); N = N_DRUG; chunk = 16; }
    __shared__ int sums[256];
    int base = t * chunk;
    int s = 0;
    for (int j = 0; j < chunk; ++j) s += cnt[base + j];
    sums[t] = s; __syncthreads();
    for (int off = 1; off < 256; off <<= 1) {
        int v = (t >= off) ? sums[t - off] : 0;
        __syncthreads();
        sums[t] += v;
        __syncthreads();
    }
    int run = sums[t] - s;
    for (int j = 0; j < chunk; ++j) { start[base + j] = run; run += cnt[base + j]; }
    if (t == 255) start[N] = run;
}

// ---------------- K4: fill CSR slots (srow, scoef) ----------------
__global__ __launch_bounds__(256) void k_fill(const int* __restrict__ ec, const int* __restrict__ ed,
                                              float* __restrict__ ws) {
    int i = blockIdx.x * 256 + threadIdx.x;
    const int* edges; const float* ew; const float* dinv; const int* start;
    int* cur; int* srow; float* scoef; int E, idx;
    if (i < E_CELL) {
        idx = i; edges = ec; E = E_CELL;
        ew = ws + OFF_EW_C; dinv = ws + OFF_DEG_C; start = (const int*)(ws + OFF_START_C);
        cur = (int*)(ws + OFF_CUR_C); srow = (int*)(ws + OFF_SROW_C); scoef = ws + OFF_SCOEF_C;
    } else {
        idx = i - E_CELL; if (idx >= E_DRUG) return;
        edges = ed; E = E_DRUG;
        ew = ws + OFF_EW_D; dinv = ws + OFF_DEG_D; start = (const int*)(ws + OFF_START_D);
        cur = (int*)(ws + OFF_CUR_D); srow = (int*)(ws + OFF_SROW_D); scoef = ws + OFF_SCOEF_D;
    }
    int r = edges[idx], c = edges[E + idx];
    float coef = dinv[r] * ew[idx] * dinv[c];
    int slot = start[c] + atomicAdd(&cur[c], 1);
    srow[slot] = r;
    scoef[slot] = coef;
}

// ---------------- K5: GEMM reading bf16 A from ws (d_in never touched) ----------------
// r13 skeleton: 32x128 tile, BK=128/iter, 16 iters (K-chunk 2048), B reg-double-buffered
// one iteration ahead, A reg+LDS dbuf 2 deep, plain-store partials.
__global__ __launch_bounds__(256, 4) void k_gemm_b(const unsigned short* __restrict__ xbC,
                                                   const unsigned short* __restrict__ xbD,
                                                   const unsigned short* __restrict__ wtc,
                                                   const unsigned short* __restrict__ wtd,
                                                   float* __restrict__ partC, float* __restrict__ partD) {
    int bid = blockIdx.x, t = threadIdx.x;
    const unsigned short* xb; const unsigned short* wt; float* part; int K, mt, ch; size_t pstride;
    if (bid < 1024) {
        xb = xbC; wt = wtc; part = partC; K = N_CELL;
        mt = bid >> 2; ch = bid & 3; pstride = (size_t)N_CELL * DOUT;
    } else {
        int b = bid - 1024; xb = xbD; wt = wtd; part = partD; K = N_DRUG;
        mt = b >> 1; ch = b & 1; pstride = (size_t)N_DRUG * DOUT;
    }
    int k0 = ch * 2048;

    __shared__ alignas(16) unsigned short As[2][32][136];
    int lane = t & 63, wv = t >> 6;
    int l15 = lane & 15, l4 = lane >> 4;

    f32x4 acc00 = {}, acc01 = {}, acc10 = {}, acc11 = {};

    int srow = t >> 3, sseg = t & 7;
    const unsigned short* abase = xb + (size_t)(mt * 32 + srow) * K + k0 + sseg * 16;
    const unsigned short* bb  = wt + (size_t)(wv * 32 + l15) * K + k0 + l4 * 8;
    const unsigned short* bb1 = bb + (size_t)16 * K;

    s16x8 X0, X1;
    s16x8 BA0, BA1, BA2, BA3, BA4, BA5, BA6, BA7;
    s16x8 BB0, BB1, BB2, BB3, BB4, BB5, BB6, BB7;

#define LOADA(IT) { X0 = *(const s16x8*)(abase + (size_t)(IT) * 128); \
                    X1 = *(const s16x8*)(abase + (size_t)(IT) * 128 + 8); }
#define WRITEA(BUF) { *(s16x8*)&As[BUF][srow][sseg * 16]     = X0; \
                      *(s16x8*)&As[BUF][srow][sseg * 16 + 8] = X1; }
#define BLOADM(P0,P1,P2,P3,P4,P5,P6,P7, IT) { \
    P0 = *(const s16x8*)(bb  + (size_t)(IT) * 128); \
    P1 = *(const s16x8*)(bb  + (size_t)(IT) * 128 + 32); \
    P2 = *(const s16x8*)(bb  + (size_t)(IT) * 128 + 64); \
    P3 = *(const s16x8*)(bb  + (size_t)(IT) * 128 + 96); \
    P4 = *(const s16x8*)(bb1 + (size_t)(IT) * 128); \
    P5 = *(const s16x8*)(bb1 + (size_t)(IT) * 128 + 32); \
    P6 = *(const s16x8*)(bb1 + (size_t)(IT) * 128 + 64); \
    P7 = *(const s16x8*)(bb1 + (size_t)(IT) * 128 + 96); }
#define COMPUTEM(BUF, B0,B1,B2,B3,B4,B5,B6,B7) { \
    { s16x8 a0 = *(const s16x8*)&As[BUF][l15][l4 * 8]; \
      s16x8 a1 = *(const s16x8*)&As[BUF][16 + l15][l4 * 8]; \
      acc00 = __builtin_amdgcn_mfma_f32_16x16x32_bf16(a0, B0, acc00, 0, 0, 0); \
      acc01 = __builtin_amdgcn_mfma_f32_16x16x32_bf16(a0, B4, acc01, 0, 0, 0); \
      acc10 = __builtin_amdgcn_mfma_f32_16x16x32_bf16(a1, B0, acc10, 0, 0, 0); \
      acc11 = __builtin_amdgcn_mfma_f32_16x16x32_bf16(a1, B4, acc11, 0, 0, 0); } \
    { s16x8 a0 = *(const s16x8*)&As[BUF][l15][32 + l4 * 8]; \
      s16x8 a1 = *(const s16x8*)&As[BUF][16 + l15][32 + l4 * 8]; \
      acc00 = __builtin_amdgcn_mfma_f32_16x16x32_bf16(a0, B1, acc00, 0, 0, 0); \
      acc01 = __builtin_amdgcn_mfma_f32_16x16x32_bf16(a0, B5, acc01, 0, 0, 0); \
      acc10 = __builtin_amdgcn_mfma_f32_16x16x32_bf16(a1, B1, acc10, 0, 0, 0); \
      acc11 = __builtin_amdgcn_mfma_f32_16x16x32_bf16(a1, B5, acc11, 0, 0, 0); } \
    { s16x8 a0 = *(const s16x8*)&As[BUF][l15][64 + l4 * 8]; \
      s16x8 a1 = *(const s16x8*)&As[BUF][16 + l15][64 + l4 * 8]; \
      acc00 = __builtin_amdgcn_mfma_f32_16x16x32_bf16(a0, B2, acc00, 0, 0, 0); \
      acc01 = __builtin_amdgcn_mfma_f32_16x16x32_bf16(a0, B6, acc01, 0, 0, 0); \
      acc10 = __builtin_amdgcn_mfma_f32_16x16x32_bf16(a1, B2, acc10, 0, 0, 0); \
      acc11 = __builtin_amdgcn_mfma_f32_16x16x32_bf16(a1, B6, acc11, 0, 0, 0); } \
    { s16x8 a0 = *(const s16x8*)&As[BUF][l15][96 + l4 * 8]; \
      s16x8 a1 = *(const s16x8*)&As[BUF][16 + l15][96 + l4 * 8]; \
      acc00 = __builtin_amdgcn_mfma_f32_16x16x32_bf16(a0, B3, acc00, 0, 0, 0); \
      acc01 = __builtin_amdgcn_mfma_f32_16x16x32_bf16(a0, B7, acc01, 0, 0, 0); \
      acc10 = __builtin_amdgcn_mfma_f32_16x16x32_bf16(a1, B3, acc10, 0, 0, 0); \
      acc11 = __builtin_amdgcn_mfma_f32_16x16x32_bf16(a1, B7, acc11, 0, 0, 0); } }

    LOADA(0);
    WRITEA(0);
    LOADA(1);
    BLOADM(BA0,BA1,BA2,BA3,BA4,BA5,BA6,BA7, 0);
    __syncthreads();

#pragma unroll 1
    for (int it2 = 0; it2 < 8; ++it2) {
        int itE = it2 * 2, itO = itE + 1;
        BLOADM(BB0,BB1,BB2,BB3,BB4,BB5,BB6,BB7, itO);
        WRITEA(itO & 1);
        if (itE < 14) LOADA(itE + 2);
        COMPUTEM(itE & 1, BA0,BA1,BA2,BA3,BA4,BA5,BA6,BA7);
        __syncthreads();
        if (itO < 15) {
            BLOADM(BA0,BA1,BA2,BA3,BA4,BA5,BA6,BA7, itO + 1);
            WRITEA((itO + 1) & 1);
            if (itO < 14) LOADA(itO + 2);
        }
        COMPUTEM(itO & 1, BB0,BB1,BB2,BB3,BB4,BB5,BB6,BB7);
        __syncthreads();
    }
#undef LOADA
#undef WRITEA
#undef BLOADM
#undef COMPUTEM
    float* dst = part + (size_t)ch * pstride;
#pragma unroll
    for (int m = 0; m < 2; ++m)
#pragma unroll
        for (int n = 0; n < 2; ++n) {
            f32x4 a = (m == 0) ? (n == 0 ? acc00 : acc01) : (n == 0 ? acc10 : acc11);
            int col = wv * 32 + n * 16 + l15;
            int row = mt * 32 + m * 16 + l4 * 4;
#pragma unroll
            for (int j = 0; j < 4; ++j)
                dst[(size_t)(row + j) * DOUT + col] = a[j];
        }
}

// ---------------- K5-fallback: r13 kernel (f32 A from d_in), used if ws too small ----
__global__ __launch_bounds__(256, 3) void k_gemm_f(const float* __restrict__ xc, const float* __restrict__ xd,
                                                   const unsigned short* __restrict__ wtc,
                                                   const unsigned short* __restrict__ wtd,
                                                   float* __restrict__ ws,
                                                   float* __restrict__ partC, float* __restrict__ partD,
                                                   int usePart) {
    int bid = blockIdx.x, t = threadIdx.x;
    const float* x; const unsigned short* wt; float* hp; float* part; int K, mt, ch; size_t pstride;
    if (bid < 1024) {
        x = xc; wt = wtc; hp = ws + OFF_H_C; part = partC; K = N_CELL;
        mt = bid >> 2; ch = bid & 3; pstride = (size_t)N_CELL * DOUT;
    } else {
        int b = bid - 1024; x = xd; wt = wtd; hp = ws + OFF_H_D; part = partD; K = N_DRUG;
        mt = b >> 1; ch = b & 1; pstride = (size_t)N_DRUG * DOUT;
    }
    int k0 = ch * 2048;
    __shared__ alignas(16) unsigned short As[2][32][136];
    int lane = t & 63, wv = t >> 6;
    int l15 = lane & 15, l4 = lane >> 4;
    f32x4 acc00 = {}, acc01 = {}, acc10 = {}, acc11 = {};
    int srow = t >> 3, sseg = t & 7;
    const float* abase = x + (size_t)(mt * 32 + srow) * K + k0 + sseg * 16;
    const unsigned short* bb  = wt + (size_t)(wv * 32 + l15) * K + k0 + l4 * 8;
    const unsigned short* bb1 = bb + (size_t)16 * K;
    float4 X0, X1, X2, X3;
#pragma unroll 1
    for (int it = 0; it < 16; ++it) {
        const float4* p = (const float4*)(abase + (size_t)it * 128);
        X0 = p[0]; X1 = p[1]; X2 = p[2]; X3 = p[3];
        *(s16x8*)&As[it & 1][srow][sseg * 16]     = pack8(X0, X1);
        *(s16x8*)&As[it & 1][srow][sseg * 16 + 8] = pack8(X2, X3);
        __syncthreads();
#pragma unroll
        for (int ks = 0; ks < 4; ++ks) {
            s16x8 b0 = *(const s16x8*)(bb  + (size_t)it * 128 + ks * 32);
            s16x8 b1 = *(const s16x8*)(bb1 + (size_t)it * 128 + ks * 32);
            s16x8 a0 = *(const s16x8*)&As[it & 1][l15][ks * 32 + l4 * 8];
            s16x8 a1 = *(const s16x8*)&As[it & 1][16 + l15][ks * 32 + l4 * 8];
            acc00 = __builtin_amdgcn_mfma_f32_16x16x32_bf16(a0, b0, acc00, 0, 0, 0);
            acc01 = __builtin_amdgcn_mfma_f32_16x16x32_bf16(a0, b1, acc01, 0, 0, 0);
            acc10 = __builtin_amdgcn_mfma_f32_16x16x32_bf16(a1, b0, acc10, 0, 0, 0);
            acc11 = __builtin_amdgcn_mfma_f32_16x16x32_bf16(a1, b1, acc11, 0, 0, 0);
        }
        __syncthreads();
    }
#pragma unroll
    for (int m = 0; m < 2; ++m)
#pragma unroll
        for (int n = 0; n < 2; ++n) {
            f32x4 a = (m == 0) ? (n == 0 ? acc00 : acc01) : (n == 0 ? acc10 : acc11);
            int col = wv * 32 + n * 16 + l15;
            int row = mt * 32 + m * 16 + l4 * 4;
#pragma unroll
            for (int j = 0; j < 4; ++j) {
                if (usePart) part[(size_t)ch * pstride + (size_t)(row + j) * DOUT + col] = a[j];
                else unsafeAtomicAdd(&hp[(size_t)(row + j) * DOUT + col], a[j]);
            }
        }
}

// ---------------- K5b: reduce partials -> h (coalesced) ----------------
__global__ __launch_bounds__(256) void k_reduce(const float* __restrict__ partC,
                                                const float* __restrict__ partD,
                                                float* __restrict__ ws) {
    int bid = blockIdx.x, t = threadIdx.x;
    if (bid < 1024) {
        size_t i = (size_t)bid * 256 + t;
        const f32x4* p = (const f32x4*)partC;
        f32x4 s = p[i] + p[i + 262144] + p[i + 2 * 262144] + p[i + 3 * 262144];
        ((f32x4*)(ws + OFF_H_C))[i] = s;
    } else {
        size_t i = (size_t)(bid - 1024) * 256 + t;
        const f32x4* p = (const f32x4*)partD;
        f32x4 s = p[i] + p[i + 131072];
        ((f32x4*)(ws + OFF_H_D))[i] = s;
    }
}

// ---------------- K6: CSR gather + self loop + bias + relu ----------------
__global__ __launch_bounds__(256) void k_gather(const float* __restrict__ ws,
                                                const float* __restrict__ bc, const float* __restrict__ bd,
                                                float* __restrict__ out) {
    int wv = threadIdx.x >> 6, lane = threadIdx.x & 63;
    int g = blockIdx.x * 4 + wv;
    const float* h; const int* srow; const float* scoef; const int* start; const float* dinv;
    const float* bvec; float* outp; int node;
    if (g < N_CELL) {
        node = g; h = ws + OFF_H_C; srow = (const int*)(ws + OFF_SROW_C); scoef = ws + OFF_SCOEF_C;
        start = (const int*)(ws + OFF_START_C); dinv = ws + OFF_DEG_C; bvec = bc; outp = out;
    } else {
        node = g - N_CELL; if (node >= N_DRUG) return;
        h = ws + OFF_H_D; srow = (const int*)(ws + OFF_SROW_D); scoef = ws + OFF_SCOEF_D;
        start = (const int*)(ws + OFF_START_D); dinv = ws + OFF_DEG_D; bvec = bd;
        outp = out + (size_t)N_CELL * DOUT;
    }
    float di = dinv[node], sc = di * di;
    float2 v = ((const float2*)(h + (size_t)node * DOUT))[lane];
    float ax = sc * v.x, ay = sc * v.y;
    int s0 = start[node], s1 = start[node + 1];
    int e = s0;
    for (; e + 3 < s1; e += 4) {
        int r0 = srow[e];     float c0 = scoef[e];
        int r1 = srow[e + 1]; float c1 = scoef[e + 1];
        int r2 = srow[e + 2]; float c2 = scoef[e + 2];
        int r3 = srow[e + 3]; float c3 = scoef[e + 3];
        float2 u0 = ((const float2*)(h + (size_t)r0 * DOUT))[lane];
        float2 u1 = ((const float2*)(h + (size_t)r1 * DOUT))[lane];
        float2 u2 = ((const float2*)(h + (size_t)r2 * DOUT))[lane];
        float2 u3 = ((const float2*)(h + (size_t)r3 * DOUT))[lane];
        ax += c0 * u0.x + c1 * u1.x + c2 * u2.x + c3 * u3.x;
        ay += c0 * u0.y + c1 * u1.y + c2 * u2.y + c3 * u3.y;
    }
    for (; e < s1; ++e) {
        int r = srow[e]; float cf = scoef[e];
        float2 u = ((const float2*)(h + (size_t)r * DOUT))[lane];
        ax += cf * u.x; ay += cf * u.y;
    }
    float2 bb = ((const float2*)bvec)[lane];
    ax = fmaxf(ax + bb.x, 0.f);
    ay = fmaxf(ay + bb.y, 0.f);
    float2 o; o.x = ax; o.y = ay;
    ((float2*)outp)[(size_t)node * 64 + lane] = o;
}

// ---------------- host ----------------
extern "C" void kernel_launch(void* const* d_in, const int* in_sizes, int n_in,
                              void* d_out, int out_size, void* d_ws, size_t ws_size,
                              hipStream_t stream) {
    const float* cell_feat = (const float*)d_in[0];
    const int*   cell_edge = (const int*)d_in[1];
    const float* W_cell    = (const float*)d_in[2];
    const float* b_cell    = (const float*)d_in[3];
    const float* drug_feat = (const float*)d_in[4];
    const int*   drug_edge = (const int*)d_in[5];
    const float* W_drug    = (const float*)d_in[6];
    const float* b_drug    = (const float*)d_in[7];
    float* out = (float*)d_out;
    float* ws  = (float*)d_ws;
    unsigned short* wtc = (unsigned short*)((char*)d_ws + WT_C_BYTE);
    unsigned short* wtd = (unsigned short*)((char*)d_ws + WT_D_BYTE);
    float* partC = (float*)((char*)d_ws + PART_C_BYTE);
    float* partD = (float*)((char*)d_ws + PART_D_BYTE);
    unsigned short* xbC = (unsigned short*)((char*)d_ws + XB_C_BYTE);
    unsigned short* xbD = (unsigned short*)((char*)d_ws + XB_D_BYTE);
    int useCast = (ws_size >= (size_t)XB_END) ? 1 : 0;
    int usePart = (ws_size >= (size_t)PART_END) ? 1 : 0;

    k_prep<<<3216, 256, 0, stream>>>(W_cell, W_drug, wtc, wtd, ws);
    k_edge<<<(E_CELL + E_DRUG) / 256, 256, 0, stream>>>(cell_feat, cell_edge, drug_feat, drug_edge, ws);
    k_scan2<<<50, 256, 0, stream>>>(ws);
    k_fill<<<1536, 256, 0, stream>>>(cell_edge, drug_edge, ws);
    if (useCast) {
        k_cast<<<2048, 256, 0, stream>>>(cell_feat, drug_feat, xbC, xbD);
        k_gemm_b<<<1280, 256, 0, stream>>>(xbC, xbD, wtc, wtd, partC, partD);
        k_reduce<<<1536, 256, 0, stream>>>(partC, partD, ws);
    } else {
        k_gemm_f<<<1280, 256, 0, stream>>>(cell_feat, drug_feat, wtc, wtd, ws, partC, partD, usePart);
        if (usePart) k_reduce<<<1536, 256, 0, stream>>>(partC, partD, ws);
    }
    k_gather<<<3072, 256, 0, stream>>>(ws, b_cell, b_drug, out);
}

// Round 15
// 288.457 us; speedup vs baseline: 1.0279x; 1.0279x over previous
//
#include <hip/hip_runtime.h>
#include <stdint.h>

#define N_CELL 8192
#define N_DRUG 4096
#define E_CELL 262144
#define E_DRUG 131072
#define DOUT   128

typedef float f32x4 __attribute__((ext_vector_type(4)));
typedef short s16x8 __attribute__((ext_vector_type(8)));

// ---------------- workspace layout (float32 element offsets) ----------------
#define OFF_DEG_C   0u
#define OFF_DEG_D   8192u
#define OFF_CNT_C   12288u
#define OFF_CNT_D   20480u
#define OFF_CUR_C   24576u
#define OFF_CUR_D   32768u
#define OFF_START_C 36864u
#define OFF_START_D 45312u
#define OFF_EW_C    49664u
#define OFF_EW_D    311808u
#define OFF_SROW_C  442880u
#define OFF_SROW_D  705024u
#define OFF_SCOEF_C 836096u
#define OFF_SCOEF_D 1098240u
#define OFF_H_C     1229312u
#define OFF_H_D     2277888u
#define OFF_END     2802176u
// byte offsets past the f32 region
#define WT_C_BYTE   (OFF_END * 4u)                   // 11,208,704
#define WT_D_BYTE   (WT_C_BYTE + 128u * 8192u * 2u)  // 13,305,856
#define PART_C_BYTE 14354432u                        // 8 x 4MB  = 33,554,432
#define PART_D_BYTE 47908864u                        // 4 x 2MB  =  8,388,608
#define PART_END    56297472u

__device__ __forceinline__ unsigned short f2bf(float f) {
    union { float f; uint32_t u; } v; v.f = f;
    uint32_t u = v.u + 0x7fffu + ((v.u >> 16) & 1u);   // RNE
    return (unsigned short)(u >> 16);
}

// pack 8 f32 -> 8 bf16 (round-half-up) via v_perm
__device__ __forceinline__ s16x8 pack8(float4 x, float4 y) {
    union { float4 f; uint32_t u[4]; } a, b;
    a.f = x; b.f = y;
    union { uint32_t u[4]; s16x8 v; } r;
    r.u[0] = __builtin_amdgcn_perm(a.u[1] + 0x8000u, a.u[0] + 0x8000u, 0x07060302u);
    r.u[1] = __builtin_amdgcn_perm(a.u[3] + 0x8000u, a.u[2] + 0x8000u, 0x07060302u);
    r.u[2] = __builtin_amdgcn_perm(b.u[1] + 0x8000u, b.u[0] + 0x8000u, 0x07060302u);
    r.u[3] = __builtin_amdgcn_perm(b.u[3] + 0x8000u, b.u[2] + 0x8000u, 0x07060302u);
    return r.v;
}

// ---------------- K1: prep = init counters + zero h + build WT bf16 ----------------
__global__ __launch_bounds__(256) void k_prep(const float* __restrict__ Wc, const float* __restrict__ Wd,
                                              unsigned short* __restrict__ wtc, unsigned short* __restrict__ wtd,
                                              float* __restrict__ ws) {
    int bid = blockIdx.x, t = threadIdx.x;
    if (bid < 144) {
        int i = bid * 256 + t;
        ws[i] = (i < 12288) ? 1.0f : 0.0f;
        return;
    }
    if (bid < 1680) {
        size_t i = (size_t)(bid - 144) * 256 + t;
        ((float4*)(ws + OFF_H_C))[i] = make_float4(0.f, 0.f, 0.f, 0.f);
        return;
    }
    int tile = bid - 1680;
    const float* W; unsigned short* wt; int K;
    if (tile < 1024) { W = Wc; wt = wtc; K = N_CELL; }
    else             { W = Wd; wt = wtd; K = N_DRUG; tile -= 1024; }
    int tk = tile >> 2, tc = tile & 3;
    __shared__ float tl[32][33];
    int c = t & 31, r8 = t >> 5;
#pragma unroll
    for (int p = 0; p < 4; ++p) {
        int row = r8 + p * 8;
        tl[row][c] = W[(size_t)(tk * 32 + row) * DOUT + tc * 32 + c];
    }
    __syncthreads();
#pragma unroll
    for (int p = 0; p < 4; ++p) {
        int c2 = r8 + p * 8;
        wt[(size_t)(tc * 32 + c2) * K + tk * 32 + c] = f2bf(tl[c][c2]);
    }
}

// ---------------- K2: ew gather + deg atomic + incoming-edge count ----------------
__global__ __launch_bounds__(256) void k_edge(const float* __restrict__ xc, const int* __restrict__ ec,
                                              const float* __restrict__ xd, const int* __restrict__ ed,
                                              float* __restrict__ ws) {
    int i = blockIdx.x * 256 + threadIdx.x;
    const float* x; const int* edges; float* ew; float* deg; int* cnt; int N, E, idx;
    if (i < E_CELL) {
        idx = i; x = xc; edges = ec; N = N_CELL; E = E_CELL;
        ew = ws + OFF_EW_C; deg = ws + OFF_DEG_C; cnt = (int*)(ws + OFF_CNT_C);
    } else {
        idx = i - E_CELL; if (idx >= E_DRUG) return;
        x = xd; edges = ed; N = N_DRUG; E = E_DRUG;
        ew = ws + OFF_EW_D; deg = ws + OFF_DEG_D; cnt = (int*)(ws + OFF_CNT_D);
    }
    int r = edges[idx], c = edges[E + idx];
    float w = x[(size_t)r * N + c];
    ew[idx] = w;
    unsafeAtomicAdd(&deg[c], w);
    atomicAdd(&cnt[c], 1);
}

// ---------------- K3: dinv (blocks 0..47) + exclusive scan (blocks 48,49) ----------------
__global__ __launch_bounds__(256) void k_scan2(float* ws) {
    int bid = blockIdx.x, t = threadIdx.x;
    if (bid < 48) {
        int i = bid * 256 + t;
        float d = ws[i];
        ws[i] = d > 0.f ? rsqrtf(fmaxf(d, 1e-30f)) : 0.f;
        return;
    }
    const int* cnt; int* start; int N, chunk;
    if (bid == 48) { cnt = (const int*)(ws + OFF_CNT_C); start = (int*)(ws + OFF_START_C); N = N_CELL; chunk = 32; }
    else           { cnt = (const int*)(ws + OFF_CNT_D); start = (int*)(ws + OFF_START_D); N = N_DRUG; chunk = 16; }
    __shared__ int sums[256];
    int base = t * chunk;
    int s = 0;
    for (int j = 0; j < chunk; ++j) s += cnt[base + j];
    sums[t] = s; __syncthreads();
    for (int off = 1; off < 256; off <<= 1) {
        int v = (t >= off) ? sums[t - off] : 0;
        __syncthreads();
        sums[t] += v;
        __syncthreads();
    }
    int run = sums[t] - s;
    for (int j = 0; j < chunk; ++j) { start[base + j] = run; run += cnt[base + j]; }
    if (t == 255) start[N] = run;
}

// ---------------- K4: fill CSR slots (srow, scoef) ----------------
__global__ __launch_bounds__(256) void k_fill(const int* __restrict__ ec, const int* __restrict__ ed,
                                              float* __restrict__ ws) {
    int i = blockIdx.x * 256 + threadIdx.x;
    const int* edges; const float* ew; const float* dinv; const int* start;
    int* cur; int* srow; float* scoef; int E, idx;
    if (i < E_CELL) {
        idx = i; edges = ec; E = E_CELL;
        ew = ws + OFF_EW_C; dinv = ws + OFF_DEG_C; start = (const int*)(ws + OFF_START_C);
        cur = (int*)(ws + OFF_CUR_C); srow = (int*)(ws + OFF_SROW_C); scoef = ws + OFF_SCOEF_C;
    } else {
        idx = i - E_CELL; if (idx >= E_DRUG) return;
        edges = ed; E = E_DRUG;
        ew = ws + OFF_EW_D; dinv = ws + OFF_DEG_D; start = (const int*)(ws + OFF_START_D);
        cur = (int*)(ws + OFF_CUR_D); srow = (int*)(ws + OFF_SROW_D); scoef = ws + OFF_SCOEF_D;
    }
    int r = edges[idx], c = edges[E + idx];
    float coef = dinv[r] * ew[idx] * dinv[c];
    int slot = start[c] + atomicAdd(&cur[c], 1);
    srow[slot] = r;
    scoef[slot] = coef;
}

// ---------------- K5: GEMM with load-free MFMA intervals ----------------
// Diagnosis r14: ~4500 cyc drained per barrier interval regardless of bytes (compiler's
// vmcnt(0) before s_barrier). Fix: per 256-K sub-chunk, stage B to LDS + A fully to
// registers, then ONE barrier pair guards a pure {64 ds_read + 128 MFMA}/wave interval
// (~2600 cyc of work per drain vs r13's 80). No global loads inside the MFMA loop.
// Block = 128 rows x 128 cols; 4 waves row-split (32 rows each); 4 sub-chunks (K-chunk 1024).
// LDS: Bs[128][264] ushort = 67,584 B (264 stride: 16B-aligned rows, near-uniform banks).
// cell: 64 mt x 8 ch = 512 blocks; drug: 32 mt x 4 ch = 128. Grid 640 = 2 blocks/CU.
// Epilogue: plain stores to disjoint partials (cell 8, drug 4) + k_reduce; atomic fallback.
__global__ __launch_bounds__(256, 2) void k_gemm2(const float* __restrict__ xc, const float* __restrict__ xd,
                                                  const unsigned short* __restrict__ wtc,
                                                  const unsigned short* __restrict__ wtd,
                                                  float* __restrict__ ws,
                                                  float* __restrict__ partC, float* __restrict__ partD,
                                                  int usePart) {
    int bid = blockIdx.x, t = threadIdx.x;
    const float* x; const unsigned short* wt; float* hp; float* part; int K, mt, ch; size_t pstride;
    if (bid < 512) {
        x = xc; wt = wtc; hp = ws + OFF_H_C; part = partC; K = N_CELL;
        mt = bid >> 3; ch = bid & 7; pstride = (size_t)N_CELL * DOUT;
    } else {
        int b = bid - 512; x = xd; wt = wtd; hp = ws + OFF_H_D; part = partD; K = N_DRUG;
        mt = b >> 2; ch = b & 3; pstride = (size_t)N_DRUG * DOUT;
    }
    int k0 = ch << 10;                                   // K-chunk base (1024)
    int rowbase = mt * 128;

    __shared__ unsigned short Bs[128 * 264];             // 67,584 B
    int lane = t & 63, wv = t >> 6;
    int l15 = lane & 15, l4 = lane >> 4;

    f32x4 acc[2][8] = {};
    s16x8 af[2][8];

    // B stage mapping: thread covers col = t>>1, half = t&1 (128 bf16 contiguous)
    int bcol = t >> 1, bhalf = t & 1;
    const unsigned short* bsrc = wt + (size_t)bcol * K + k0 + bhalf * 128;
    unsigned bdst = (unsigned)bcol * 264u + (unsigned)bhalf * 128u;
    // A fragment rows for this wave
    int arow0 = rowbase + wv * 32 + l15;
    const float* ap0 = x + (size_t)arow0 * K + k0 + l4 * 8;
    const float* ap1 = ap0 + (size_t)16 * K;

#pragma unroll 1
    for (int kc = 0; kc < 4; ++kc) {
        __syncthreads();                                  // prev sub-chunk's LDS reads done
        // ---- stage B[128][256] bf16 -> LDS (16 loads + 16 ds_writes / thread) ----
#pragma unroll
        for (int j = 0; j < 16; ++j) {
            s16x8 v = *(const s16x8*)(bsrc + kc * 256 + j * 8);
            *(s16x8*)&Bs[bdst + (unsigned)j * 8u] = v;
        }
        // ---- load ALL A for this sub-chunk into registers (32 float4/lane -> 16 bf16x8) ----
#pragma unroll
        for (int js = 0; js < 8; ++js) {
            const float4* p0 = (const float4*)(ap0 + kc * 256 + js * 32);
            const float4* p1 = (const float4*)(ap1 + kc * 256 + js * 32);
            af[0][js] = pack8(p0[0], p0[1]);
            af[1][js] = pack8(p1[0], p1[1]);
        }
        __syncthreads();                                  // B visible (drain hits done loads)
        // ---- pure compute interval: 64 ds_read + 128 MFMA per wave, zero global loads ----
#pragma unroll
        for (int js = 0; js < 8; ++js) {
#pragma unroll
            for (int cg = 0; cg < 8; ++cg) {
                s16x8 b = *(const s16x8*)&Bs[(unsigned)(cg * 16 + l15) * 264u + (unsigned)(js * 32 + l4 * 8)];
                acc[0][cg] = __builtin_amdgcn_mfma_f32_16x16x32_bf16(af[0][js], b, acc[0][cg], 0, 0, 0);
                acc[1][cg] = __builtin_amdgcn_mfma_f32_16x16x32_bf16(af[1][js], b, acc[1][cg], 0, 0, 0);
            }
        }
    }
    // ---- epilogue ----
    if (usePart) {
        float* dst = part + (size_t)ch * pstride;
#pragma unroll
        for (int m = 0; m < 2; ++m)
#pragma unroll
            for (int cg = 0; cg < 8; ++cg) {
                int col = cg * 16 + l15;
                int row = rowbase + wv * 32 + m * 16 + l4 * 4;
#pragma unroll
                for (int j = 0; j < 4; ++j)
                    dst[(size_t)(row + j) * DOUT + col] = acc[m][cg][j];
            }
    } else {
#pragma unroll
        for (int m = 0; m < 2; ++m)
#pragma unroll
            for (int cg = 0; cg < 8; ++cg) {
                int col = cg * 16 + l15;
                int row = rowbase + wv * 32 + m * 16 + l4 * 4;
#pragma unroll
                for (int j = 0; j < 4; ++j)
                    unsafeAtomicAdd(&hp[(size_t)(row + j) * DOUT + col], acc[m][cg][j]);
            }
    }
}

// ---------------- K5b: reduce partials -> h (cell 8 copies, drug 4) ----------------
__global__ __launch_bounds__(256) void k_reduce(const float* __restrict__ partC,
                                                const float* __restrict__ partD,
                                                float* __restrict__ ws) {
    int bid = blockIdx.x, t = threadIdx.x;
    if (bid < 1024) {
        size_t i = (size_t)bid * 256 + t;                // 262144 f32x4 = cell h
        const f32x4* p = (const f32x4*)partC;
        f32x4 s = p[i] + p[i + 262144] + p[i + 2 * 262144] + p[i + 3 * 262144]
                + p[i + 4 * 262144] + p[i + 5 * 262144] + p[i + 6 * 262144] + p[i + 7 * 262144];
        ((f32x4*)(ws + OFF_H_C))[i] = s;
    } else {
        size_t i = (size_t)(bid - 1024) * 256 + t;       // 131072 f32x4 = drug h
        const f32x4* p = (const f32x4*)partD;
        f32x4 s = p[i] + p[i + 131072] + p[i + 2 * 131072] + p[i + 3 * 131072];
        ((f32x4*)(ws + OFF_H_D))[i] = s;
    }
}

// ---------------- K6: CSR gather + self loop + bias + relu ----------------
__global__ __launch_bounds__(256) void k_gather(const float* __restrict__ ws,
                                                const float* __restrict__ bc, const float* __restrict__ bd,
                                                float* __restrict__ out) {
    int wv = threadIdx.x >> 6, lane = threadIdx.x & 63;
    int g = blockIdx.x * 4 + wv;
    const float* h; const int* srow; const float* scoef; const int* start; const float* dinv;
    const float* bvec; float* outp; int node;
    if (g < N_CELL) {
        node = g; h = ws + OFF_H_C; srow = (const int*)(ws + OFF_SROW_C); scoef = ws + OFF_SCOEF_C;
        start = (const int*)(ws + OFF_START_C); dinv = ws + OFF_DEG_C; bvec = bc; outp = out;
    } else {
        node = g - N_CELL; if (node >= N_DRUG) return;
        h = ws + OFF_H_D; srow = (const int*)(ws + OFF_SROW_D); scoef = ws + OFF_SCOEF_D;
        start = (const int*)(ws + OFF_START_D); dinv = ws + OFF_DEG_D; bvec = bd;
        outp = out + (size_t)N_CELL * DOUT;
    }
    float di = dinv[node], sc = di * di;
    float2 v = ((const float2*)(h + (size_t)node * DOUT))[lane];
    float ax = sc * v.x, ay = sc * v.y;
    int s0 = start[node], s1 = start[node + 1];
    int e = s0;
    for (; e + 3 < s1; e += 4) {
        int r0 = srow[e];     float c0 = scoef[e];
        int r1 = srow[e + 1]; float c1 = scoef[e + 1];
        int r2 = srow[e + 2]; float c2 = scoef[e + 2];
        int r3 = srow[e + 3]; float c3 = scoef[e + 3];
        float2 u0 = ((const float2*)(h + (size_t)r0 * DOUT))[lane];
        float2 u1 = ((const float2*)(h + (size_t)r1 * DOUT))[lane];
        float2 u2 = ((const float2*)(h + (size_t)r2 * DOUT))[lane];
        float2 u3 = ((const float2*)(h + (size_t)r3 * DOUT))[lane];
        ax += c0 * u0.x + c1 * u1.x + c2 * u2.x + c3 * u3.x;
        ay += c0 * u0.y + c1 * u1.y + c2 * u2.y + c3 * u3.y;
    }
    for (; e < s1; ++e) {
        int r = srow[e]; float cf = scoef[e];
        float2 u = ((const float2*)(h + (size_t)r * DOUT))[lane];
        ax += cf * u.x; ay += cf * u.y;
    }
    float2 bb = ((const float2*)bvec)[lane];
    ax = fmaxf(ax + bb.x, 0.f);
    ay = fmaxf(ay + bb.y, 0.f);
    float2 o; o.x = ax; o.y = ay;
    ((float2*)outp)[(size_t)node * 64 + lane] = o;
}

// ---------------- host ----------------
extern "C" void kernel_launch(void* const* d_in, const int* in_sizes, int n_in,
                              void* d_out, int out_size, void* d_ws, size_t ws_size,
                              hipStream_t stream) {
    const float* cell_feat = (const float*)d_in[0];
    const int*   cell_edge = (const int*)d_in[1];
    const float* W_cell    = (const float*)d_in[2];
    const float* b_cell    = (const float*)d_in[3];
    const float* drug_feat = (const float*)d_in[4];
    const int*   drug_edge = (const int*)d_in[5];
    const float* W_drug    = (const float*)d_in[6];
    const float* b_drug    = (const float*)d_in[7];
    float* out = (float*)d_out;
    float* ws  = (float*)d_ws;
    unsigned short* wtc = (unsigned short*)((char*)d_ws + WT_C_BYTE);
    unsigned short* wtd = (unsigned short*)((char*)d_ws + WT_D_BYTE);
    float* partC = (float*)((char*)d_ws + PART_C_BYTE);
    float* partD = (float*)((char*)d_ws + PART_D_BYTE);
    int usePart = (ws_size >= (size_t)PART_END) ? 1 : 0;

    k_prep<<<3216, 256, 0, stream>>>(W_cell, W_drug, wtc, wtd, ws);
    k_edge<<<(E_CELL + E_DRUG) / 256, 256, 0, stream>>>(cell_feat, cell_edge, drug_feat, drug_edge, ws);
    k_scan2<<<50, 256, 0, stream>>>(ws);
    k_fill<<<1536, 256, 0, stream>>>(cell_edge, drug_edge, ws);
    k_gemm2<<<640, 256, 0, stream>>>(cell_feat, drug_feat, wtc, wtd, ws, partC, partD, usePart);
    if (usePart) k_reduce<<<1536, 256, 0, stream>>>(partC, partD, ws);
    k_gather<<<3072, 256, 0, stream>>>(ws, b_cell, b_drug, out);
}